// Round 5
// baseline (200.109 us; speedup 1.0000x reference)
//
#include <hip/hip_runtime.h>
#include <hip/hip_bf16.h>

#define B_ 2
#define S_ 2048
#define D_ 1024
#define H_ 16
#define DK_ 64

typedef __hip_bfloat16 bf16;
typedef short v8s __attribute__((ext_vector_type(8)));   // 8 bf16 MFMA A/B frag
typedef short v4s __attribute__((ext_vector_type(4)));
typedef float v4f __attribute__((ext_vector_type(4)));
typedef float v16f __attribute__((ext_vector_type(16))); // 32x32 MFMA C/D
typedef int   v4i __attribute__((ext_vector_type(4)));

static __device__ __forceinline__ v4f mfma16(v8s a, v8s b, v4f c) {
  return __builtin_amdgcn_mfma_f32_16x16x32_bf16(a, b, c, 0, 0, 0);
}
static __device__ __forceinline__ v16f mfma32(v8s a, v8s b, v16f c) {
  return __builtin_amdgcn_mfma_f32_32x32x16_bf16(a, b, c, 0, 0, 0);
}
static __device__ __forceinline__ void gl2lds16(const void* g, void* l) {
  __builtin_amdgcn_global_load_lds((const __attribute__((address_space(1))) void*)g,
                                   (__attribute__((address_space(3))) void*)l,
                                   16, 0, 0);
}
static __device__ __forceinline__ unsigned short bfb(float x) {
  return __builtin_bit_cast(unsigned short, __float2bfloat16(x));
}
static __device__ __forceinline__ short f2bf(float x) { return (short)bfb(x); }
static __device__ __forceinline__ int pk2(float lo, float hi) {
  return (int)(((unsigned)bfb(hi) << 16) | (unsigned)bfb(lo));
}

// ---------- pre-pass: K f32 [b][s][h*64+d] -> bf16 [bh][s][64] ----------
__global__ __launch_bounds__(256) void cvt_k_kernel(const float* __restrict__ K,
                                                    bf16* __restrict__ Kb) {
  const int idx = blockIdx.x * 256 + threadIdx.x;  // each handles 8 elems
  const int seg = idx & 7;
  const int rest = idx >> 3;
  const int h = rest & 15;
  const int bs = rest >> 4;          // b*S + s
  const float* src = K + (size_t)bs * D_ + h * 64 + seg * 8;
  v4f x = *(const v4f*)src, y = *(const v4f*)(src + 4);
  v8s r;
  r[0]=f2bf(x[0]); r[1]=f2bf(x[1]); r[2]=f2bf(x[2]); r[3]=f2bf(x[3]);
  r[4]=f2bf(y[0]); r[5]=f2bf(y[1]); r[6]=f2bf(y[2]); r[7]=f2bf(y[3]);
  const int b = bs >> 11, s = bs & 2047;
  *(v8s*)(Kb + ((size_t)(b * H_ + h) * S_ + s) * DK_ + seg * 8) = r;
}

// ---------- pre-pass: V f32 -> V^T bf16 [bh][d=64][s=2048] ----------
__global__ __launch_bounds__(256) void tv_kernel(const float* __restrict__ V,
                                                 bf16* __restrict__ Vt) {
  __shared__ __align__(16) bf16 td[64 * 72];   // [d][s_local], stride 72
  const int t = threadIdx.x;
  const int bh = blockIdx.x, b = bh >> 4, h = bh & 15;
  const int s0 = blockIdx.y * 64;
  const int srow = t >> 2;   // 0..63
  const int cs = t & 3;      // 16 d each
  const float* vp = V + (size_t)(b * S_ + s0 + srow) * D_ + h * 64 + cs * 16;
#pragma unroll
  for (int j = 0; j < 4; j++) {
    v4f x = *(const v4f*)(vp + j * 4);
#pragma unroll
    for (int jj = 0; jj < 4; jj++)
      td[(cs * 16 + j * 4 + jj) * 72 + srow] = __float2bfloat16(x[jj]);
  }
  __syncthreads();
  const int d = t >> 2, sseg = t & 3;
#pragma unroll
  for (int j = 0; j < 2; j++) {
    v8s val = *(const v8s*)(td + d * 72 + sseg * 16 + j * 8);
    *(v8s*)(Vt + ((size_t)bh * DK_ + d) * S_ + s0 + sseg * 16 + j * 8) = val;
  }
}

// ---------- pre-pass: Wo f32 -> bf16 ----------
__global__ __launch_bounds__(256) void cvt_wo_kernel(const float* __restrict__ Wo,
                                                     bf16* __restrict__ Wb) {
  const int i = (blockIdx.x * 256 + threadIdx.x) * 4;
  v4f a = *(const v4f*)(Wo + i);
  v4s r;
  r[0]=f2bf(a[0]); r[1]=f2bf(a[1]); r[2]=f2bf(a[2]); r[3]=f2bf(a[3]);
  *(v4s*)((short*)Wb + i) = r;
}

// ---------- flash attention, 32x32 MFMA, S^T/O^T register-domain softmax ----------
// grid (32 bh, 16 q-tiles of 128), block 256 = 4 waves, each wave 32 q.
__global__ __launch_bounds__(256, 2) void attn2_kernel(
    const float* __restrict__ Q, const bf16* __restrict__ Kb,
    const bf16* __restrict__ Vt, bf16* __restrict__ Ow)
{
  __shared__ __align__(16) bf16 kk[2][32 * 64];  // [key][d], XOR-swizzled segs
  __shared__ __align__(16) bf16 vv[2][64 * 32];  // [d][key], XOR-swizzled segs
  __shared__ __align__(16) bf16 ep[4][32 * 72];  // epilogue transpose [q][d]

  const int t = threadIdx.x;
  const int w = t >> 6;
  const int l = t & 63;
  const int h2 = l >> 5;     // half-wave
  const int ln = l & 31;

  const int bh = blockIdx.x;
  const int b = bh >> 4, h = bh & 15;
  const int qbase = blockIdx.y * 128 + w * 32;

  const bf16* Kbh = Kb + (size_t)bh * (S_ * DK_);
  const bf16* Vbh = Vt + (size_t)bh * (DK_ * S_);

  // staging: one gl2lds16 per thread per tile for each of K and V
  const int krow = t >> 3, ksrc_seg = (t & 7) ^ (krow & 7);
  const int vrow = t >> 2, vsrc_seg = (t & 3) ^ (vrow & 3);

  // Q^T B-frags: B[k=d][n=q]: lane holds q=ln, d = c*16 + h2*8 + j. Scale folded.
  const float sc = 0.18033688011112042f;  // (1/sqrt(64)) * log2(e)
  v8s bq[4];
  {
    const float* qp = Q + ((size_t)b * S_ + qbase + ln) * D_ + h * DK_ + h2 * 8;
#pragma unroll
    for (int c = 0; c < 4; c++) {
      v4f x = *(const v4f*)(qp + c * 16);
      v4f y = *(const v4f*)(qp + c * 16 + 4);
      v8s r;
      r[0]=f2bf(x[0]*sc); r[1]=f2bf(x[1]*sc); r[2]=f2bf(x[2]*sc); r[3]=f2bf(x[3]*sc);
      r[4]=f2bf(y[0]*sc); r[5]=f2bf(y[1]*sc); r[6]=f2bf(y[2]*sc); r[7]=f2bf(y[3]*sc);
      bq[c] = r;
    }
  }

  v16f accA, accB;
#pragma unroll
  for (int r = 0; r < 16; r++) { accA[r] = 0.f; accB[r] = 0.f; }
  float lpart = 0.f;

  // prologue: stage tile 0 into buf 0
  gl2lds16(Kbh + (size_t)krow * DK_ + ksrc_seg * 8, &kk[0][t * 8]);
  gl2lds16(Vbh + (size_t)vrow * S_ + vsrc_seg * 8, &vv[0][t * 8]);

  int it = 0;
  for (int kb = 0; kb < S_; kb += 32, it ^= 1) {
    __syncthreads();  // drains vmcnt -> current buf ready; prev readers done
    if (kb + 32 < S_) {
      gl2lds16(Kbh + (size_t)(kb + 32 + krow) * DK_ + ksrc_seg * 8, &kk[it ^ 1][t * 8]);
      gl2lds16(Vbh + (size_t)vrow * S_ + (kb + 32) + vsrc_seg * 8, &vv[it ^ 1][t * 8]);
    }
    const bf16* kc_ = kk[it];
    const bf16* vc_ = vv[it];

    // S^T = K·Q^T  (A = K[m=key][k=d] from LDS, B = Q^T regs)
    v16f s;
#pragma unroll
    for (int r = 0; r < 16; r++) s[r] = 0.f;
#pragma unroll
    for (int c = 0; c < 4; c++) {
      const int sd = 2 * c + h2;
      v8s ak = *(const v8s*)(kc_ + ln * 64 + ((sd ^ (ln & 7)) * 8));
      s = mfma32(ak, bq[c], s);
    }
    // C layout: col q = ln, row key = (r&3) + 8*(r>>2) + 4*h2

    float p[16];
#pragma unroll
    for (int r = 0; r < 16; r++) p[r] = exp2f(s[r]);
    float su = 0.f;
#pragma unroll
    for (int r = 0; r < 16; r++) su += p[r];
    lpart += su;   // own-half keys only; cross-half merge at epilogue

    // pack P pairs (keys 2g,2g+1 within own half) and swap halves
    int Pk[8], Sw[8];
#pragma unroll
    for (int g = 0; g < 8; g++) Pk[g] = pk2(p[2 * g], p[2 * g + 1]);
#pragma unroll
    for (int g = 0; g < 8; g++) Sw[g] = __shfl_xor(Pk[g], 32);

    // P^T B-frags: B[k=key][n=q=ln], k = h2*8 + j (+16 for kc=1)
    v4i b0i, b1i;
    b0i[0] = h2 ? Sw[2] : Pk[0];  b0i[1] = h2 ? Sw[3] : Pk[1];
    b0i[2] = h2 ? Pk[2] : Sw[0];  b0i[3] = h2 ? Pk[3] : Sw[1];
    b1i[0] = h2 ? Sw[6] : Pk[4];  b1i[1] = h2 ? Sw[7] : Pk[5];
    b1i[2] = h2 ? Pk[6] : Sw[4];  b1i[3] = h2 ? Pk[7] : Sw[5];
    v8s pb0 = __builtin_bit_cast(v8s, b0i);
    v8s pb1 = __builtin_bit_cast(v8s, b1i);

    // O^T += V^T · P^T  (A = V^T[m=d][k=key] from LDS)
#pragma unroll
    for (int kc = 0; kc < 2; kc++) {
      const int sk = 2 * kc + h2;
      const int dA = ln;         // d 0..31
      const int dB = 32 + ln;    // d 32..63
      v8s avA = *(const v8s*)(vc_ + dA * 32 + ((sk ^ (dA & 3)) * 8));
      v8s avB = *(const v8s*)(vc_ + dB * 32 + ((sk ^ (dB & 3)) * 8));
      accA = mfma32(avA, kc ? pb1 : pb0, accA);
      accB = mfma32(avB, kc ? pb1 : pb0, accB);
    }
  }

  // epilogue: normalize, transpose via LDS, coalesced bf16 store
  const float linv = 1.0f / (lpart + __shfl_xor(lpart, 32));
  bf16* epw = ep[w];
#pragma unroll
  for (int r = 0; r < 16; r++) {
    const int dr = (r & 3) + 8 * (r >> 2) + 4 * h2;
    epw[ln * 72 + dr]      = __float2bfloat16(accA[r] * linv);
    epw[ln * 72 + 32 + dr] = __float2bfloat16(accB[r] * linv);
  }
  __syncthreads();
#pragma unroll
  for (int i = 0; i < 4; i++) {
    const int flat = i * 64 + l;
    const int qr = flat >> 3, seg = flat & 7;
    v8s val = *(const v8s*)(epw + qr * 72 + seg * 8);
    const int srow = qbase - w * 32 + w * 32 + qr;  // qbase + qr
    *(v8s*)(Ow + ((size_t)b * S_ + qbase + qr) * D_ + h * DK_ + seg * 8) = val;
    (void)srow;
  }
}

// ---------- projection: Out[m][n] = sum_k o[m][k]*Wo[n][k], f32 out ----------
// 64x128 tile, BK=32, dbuf, grid (64, 8) = 512 blocks
__global__ __launch_bounds__(256, 2) void proj2_kernel(
    const bf16* __restrict__ A, const bf16* __restrict__ Wo, float* __restrict__ Out)
{
  __shared__ __align__(16) bf16 aa[2][64 * 32];
  __shared__ __align__(16) bf16 bb[2][128 * 32];

  const int t = threadIdx.x;
  const int w = t >> 6;
  const int l = t & 63;
  const int quad = l >> 4;
  const int lm = l & 15;

  const int m0 = blockIdx.x * 64;
  const int n0 = blockIdx.y * 128;
  const int wm = (w & 1) * 32;
  const int wn = (w >> 1) * 64;

  v4f acc[2][4];
#pragma unroll
  for (int i = 0; i < 2; i++)
#pragma unroll
    for (int j = 0; j < 4; j++)
      acc[i][j] = {0.f, 0.f, 0.f, 0.f};

  const int arow = t >> 2, aseg = t & 3;

  // prologue: k0 = 0 into buf 0
  gl2lds16(A + (size_t)(m0 + arow) * D_ + aseg * 8, &aa[0][t * 8]);
#pragma unroll
  for (int j = 0; j < 2; j++) {
    const int flat = j * 256 + t;
    gl2lds16(Wo + (size_t)(n0 + (flat >> 2)) * D_ + (flat & 3) * 8, &bb[0][flat * 8]);
  }

  int it = 0;
  for (int k0 = 0; k0 < D_; k0 += 32, it ^= 1) {
    __syncthreads();
    if (k0 + 32 < D_) {
      gl2lds16(A + (size_t)(m0 + arow) * D_ + (k0 + 32) + aseg * 8, &aa[it ^ 1][t * 8]);
#pragma unroll
      for (int j = 0; j < 2; j++) {
        const int flat = j * 256 + t;
        gl2lds16(Wo + (size_t)(n0 + (flat >> 2)) * D_ + (k0 + 32) + (flat & 3) * 8,
                 &bb[it ^ 1][flat * 8]);
      }
    }
    const bf16* ac = aa[it];
    const bf16* bc = bb[it];

    v8s am[2], bn[4];
#pragma unroll
    for (int i = 0; i < 2; i++)
      am[i] = *(const v8s*)(ac + (wm + i * 16 + lm) * 32 + quad * 8);
#pragma unroll
    for (int i = 0; i < 4; i++)
      bn[i] = *(const v8s*)(bc + (wn + i * 16 + lm) * 32 + quad * 8);
#pragma unroll
    for (int mi = 0; mi < 2; mi++)
#pragma unroll
      for (int ni = 0; ni < 4; ni++)
        acc[mi][ni] = mfma16(am[mi], bn[ni], acc[mi][ni]);
  }

#pragma unroll
  for (int mi = 0; mi < 2; mi++) {
#pragma unroll
    for (int r = 0; r < 4; r++) {
      const int row = m0 + wm + mi * 16 + quad * 4 + r;
      float* orow = Out + (size_t)row * D_ + n0 + wn + lm;
#pragma unroll
      for (int ni = 0; ni < 4; ni++)
        orow[ni * 16] = acc[mi][ni][r];
    }
  }
}

extern "C" void kernel_launch(void* const* d_in, const int* in_sizes, int n_in,
                              void* d_out, int out_size, void* d_ws, size_t ws_size,
                              hipStream_t stream) {
  (void)in_sizes; (void)n_in; (void)out_size; (void)ws_size;
  const float* Q  = (const float*)d_in[0];
  const float* K  = (const float*)d_in[1];
  const float* V  = (const float*)d_in[2];
  const float* Wo = (const float*)d_in[3];
  float* out = (float*)d_out;

  bf16* kb   = (bf16*)d_ws;                        // 8 MB: K bf16 [bh][s][64]
  bf16* vt   = kb + (size_t)4 * 1024 * 1024;       // 8 MB: V^T bf16 [bh][64][s]
  bf16* ows  = vt + (size_t)4 * 1024 * 1024;       // 8 MB: o bf16 [4096][1024]
  bf16* wo_b = ows + (size_t)4 * 1024 * 1024;      // 2 MB: Wo bf16

  cvt_k_kernel <<<dim3(2048),     256, 0, stream>>>(K, kb);
  tv_kernel    <<<dim3(32, 32),   256, 0, stream>>>(V, vt);
  cvt_wo_kernel<<<dim3(1024),     256, 0, stream>>>(Wo, wo_b);
  attn2_kernel <<<dim3(32, 16),   256, 0, stream>>>(Q, kb, vt, ows);
  proj2_kernel <<<dim3(64, 8),    256, 0, stream>>>(ows, wo_b, out);
}

// Round 6
// 178.113 us; speedup vs baseline: 1.1235x; 1.1235x over previous
//
#include <hip/hip_runtime.h>
#include <hip/hip_bf16.h>

#define B_ 2
#define S_ 2048
#define D_ 1024
#define H_ 16
#define DK_ 64

typedef __hip_bfloat16 bf16;
typedef short v8s __attribute__((ext_vector_type(8)));
typedef short v4s __attribute__((ext_vector_type(4)));
typedef float v4f __attribute__((ext_vector_type(4)));
typedef float v16f __attribute__((ext_vector_type(16)));
typedef int   v4i __attribute__((ext_vector_type(4)));

static __device__ __forceinline__ v16f mfma32(v8s a, v8s b, v16f c) {
  return __builtin_amdgcn_mfma_f32_32x32x16_bf16(a, b, c, 0, 0, 0);
}
static __device__ __forceinline__ void gl2lds16(const void* g, void* l) {
  __builtin_amdgcn_global_load_lds((const __attribute__((address_space(1))) void*)g,
                                   (__attribute__((address_space(3))) void*)l,
                                   16, 0, 0);
}
static __device__ __forceinline__ short f2bf(float x) {  // RNE (pre-passes)
  return (short)__builtin_bit_cast(unsigned short, __float2bfloat16(x));
}
// fast bf16 pair pack: round-half-up then v_perm_b32 (3 VALU per 2 values)
static __device__ __forceinline__ int pk2f(float lo, float hi) {
  unsigned a = __builtin_bit_cast(unsigned, lo) + 0x8000u;
  unsigned b = __builtin_bit_cast(unsigned, hi) + 0x8000u;
  return (int)__builtin_amdgcn_perm(b, a, 0x07060302u);
}

// ---------- pre-pass: K f32 [b][s][h*64+d] -> bf16 [bh][s][64] ----------
__global__ __launch_bounds__(256) void cvt_k_kernel(const float* __restrict__ K,
                                                    bf16* __restrict__ Kb) {
  const int idx = blockIdx.x * 256 + threadIdx.x;
  const int seg = idx & 7;
  const int rest = idx >> 3;
  const int h = rest & 15;
  const int bs = rest >> 4;
  const float* src = K + (size_t)bs * D_ + h * 64 + seg * 8;
  v4f x = *(const v4f*)src, y = *(const v4f*)(src + 4);
  v8s r;
  r[0]=f2bf(x[0]); r[1]=f2bf(x[1]); r[2]=f2bf(x[2]); r[3]=f2bf(x[3]);
  r[4]=f2bf(y[0]); r[5]=f2bf(y[1]); r[6]=f2bf(y[2]); r[7]=f2bf(y[3]);
  const int b = bs >> 11, s = bs & 2047;
  *(v8s*)(Kb + ((size_t)(b * H_ + h) * S_ + s) * DK_ + seg * 8) = r;
}

// ---------- pre-pass: V f32 -> V^T bf16 [bh][d=64][s=2048], key-PERMUTED ----------
// position p within each 32-key group holds key rho(p) = 16*(p>>4) + 4*((p>>3)&1) + (p&3) + 8*((p>>2)&1)
// so that PV A-frag k-slots match the S^T MFMA C-layout rows (no cross-lane swap needed).
__global__ __launch_bounds__(256) void tv_kernel(const float* __restrict__ V,
                                                 bf16* __restrict__ Vt) {
  __shared__ __align__(16) bf16 td[64 * 72];
  const int t = threadIdx.x;
  const int bh = blockIdx.x, b = bh >> 4, h = bh & 15;
  const int s0 = blockIdx.y * 64;
  const int srow = t >> 2;
  const int cs = t & 3;
  const float* vp = V + (size_t)(b * S_ + s0 + srow) * D_ + h * 64 + cs * 16;
#pragma unroll
  for (int j = 0; j < 4; j++) {
    v4f x = *(const v4f*)(vp + j * 4);
#pragma unroll
    for (int jj = 0; jj < 4; jj++)
      td[(cs * 16 + j * 4 + jj) * 72 + srow] = __float2bfloat16(x[jj]);
  }
  __syncthreads();
  const int d = t >> 2;
#pragma unroll
  for (int a2 = 0; a2 < 4; a2++) {
    const int pos = cs * 16 + a2 * 4;           // aligned 4-chunk of positions
    const int g = pos >> 5;                     // 32-key group
    const int a = (pos >> 2) & 7;
    const int kbase = g * 32 + ((a >> 2) << 4) + ((a & 1) << 3) + (((a >> 1) & 1) << 2);
    v4s val = *(const v4s*)(td + d * 72 + kbase);
    *(v4s*)(Vt + ((size_t)bh * DK_ + d) * S_ + s0 + pos) = val;
  }
}

// ---------- pre-pass: Wo f32 -> bf16 ----------
__global__ __launch_bounds__(256) void cvt_wo_kernel(const float* __restrict__ Wo,
                                                     bf16* __restrict__ Wb) {
  const int i = (blockIdx.x * 256 + threadIdx.x) * 4;
  v4f a = *(const v4f*)(Wo + i);
  v4s r;
  r[0]=f2bf(a[0]); r[1]=f2bf(a[1]); r[2]=f2bf(a[2]); r[3]=f2bf(a[3]);
  *(v4s*)((short*)Wb + i) = r;
}

// ---------- flash attention: 64-key steps, shuffle-free softmax ----------
// grid (32 bh, 16 q-tiles of 128), block 256 = 4 waves x 32 q
__global__ __launch_bounds__(256, 2) void attn3_kernel(
    const float* __restrict__ Q, const bf16* __restrict__ Kb,
    const bf16* __restrict__ Vt, bf16* __restrict__ Ow)
{
  __shared__ __align__(16) bf16 kk[2][64 * 64];   // [key][d], XOR-swizzled 8-elem segs
  __shared__ __align__(16) bf16 vv[2][64 * 64];   // [d][key-pos], XOR-swizzled
  __shared__ __align__(16) bf16 ep[4][32 * 72];   // epilogue transpose

  const int t = threadIdx.x;
  const int w = t >> 6, l = t & 63, h2 = l >> 5, ln = l & 31;
  const int bh = blockIdx.x, b = bh >> 4, h = bh & 15;
  const int qbase = blockIdx.y * 128 + w * 32;

  const bf16* Kbh = Kb + (size_t)bh * (S_ * DK_);
  const bf16* Vbh = Vt + (size_t)bh * (DK_ * S_);

  // Q^T B-frags, scale folded: B[k=d][n=q=ln], d = 16c + h2*8 + j
  const float sc = 0.18033688011112042f;  // (1/sqrt(64)) * log2(e)
  v8s bq[4];
  {
    const float* qp = Q + ((size_t)b * S_ + qbase + ln) * D_ + h * DK_ + h2 * 8;
#pragma unroll
    for (int c = 0; c < 4; c++) {
      v4f x = *(const v4f*)(qp + c * 16);
      v4f y = *(const v4f*)(qp + c * 16 + 4);
      v4i r = { pk2f(x[0]*sc, x[1]*sc), pk2f(x[2]*sc, x[3]*sc),
                pk2f(y[0]*sc, y[1]*sc), pk2f(y[2]*sc, y[3]*sc) };
      bq[c] = __builtin_bit_cast(v8s, r);
    }
  }

  v16f accA, accB;
#pragma unroll
  for (int r = 0; r < 16; r++) { accA[r] = 0.f; accB[r] = 0.f; }
  float lpart = 0.f;

  // prologue: stage tile 0 (keys 0..63) into buf 0
#pragma unroll
  for (int j = 0; j < 2; j++) {
    const int flat = j * 256 + t, row = flat >> 3, sp = flat & 7;
    gl2lds16(Kbh + (size_t)row * DK_ + ((sp ^ (row & 7)) * 8), &kk[0][flat * 8]);
    gl2lds16(Vbh + (size_t)row * S_ + ((sp ^ (row & 7)) * 8), &vv[0][flat * 8]);
  }

  int it = 0;
  for (int kb = 0; kb < S_; kb += 64, it ^= 1) {
    __syncthreads();
    if (kb + 64 < S_) {
#pragma unroll
      for (int j = 0; j < 2; j++) {
        const int flat = j * 256 + t, row = flat >> 3, sp = flat & 7;
        gl2lds16(Kbh + (size_t)(kb + 64 + row) * DK_ + ((sp ^ (row & 7)) * 8),
                 &kk[it ^ 1][flat * 8]);
        gl2lds16(Vbh + (size_t)row * S_ + (kb + 64) + ((sp ^ (row & 7)) * 8),
                 &vv[it ^ 1][flat * 8]);
      }
    }
    const bf16* kc_ = kk[it];
    const bf16* vc_ = vv[it];

    // two independent 32-key S^T tiles: S^T = K . Q^T
    v16f s0, s1;
#pragma unroll
    for (int r = 0; r < 16; r++) { s0[r] = 0.f; s1[r] = 0.f; }
#pragma unroll
    for (int c = 0; c < 4; c++) {
      const int sd = 2 * c + h2;
      v8s a0 = *(const v8s*)(kc_ + ln * 64 + ((sd ^ (ln & 7)) * 8));
      v8s a1 = *(const v8s*)(kc_ + (32 + ln) * 64 + ((sd ^ (ln & 7)) * 8));
      s0 = mfma32(a0, bq[c], s0);
      s1 = mfma32(a1, bq[c], s1);
    }

    float p0[16], p1[16];
#pragma unroll
    for (int r = 0; r < 16; r++) { p0[r] = exp2f(s0[r]); p1[r] = exp2f(s1[r]); }
    float su = 0.f;
#pragma unroll
    for (int r = 0; r < 16; r++) su += p0[r] + p1[r];
    lpart += su;

    // P^T B-frags directly from in-lane C values (key permutation makes slots line up)
    v4i i00 = { pk2f(p0[0],p0[1]),  pk2f(p0[2],p0[3]),  pk2f(p0[4],p0[5]),  pk2f(p0[6],p0[7]) };
    v4i i01 = { pk2f(p0[8],p0[9]),  pk2f(p0[10],p0[11]),pk2f(p0[12],p0[13]),pk2f(p0[14],p0[15]) };
    v4i i10 = { pk2f(p1[0],p1[1]),  pk2f(p1[2],p1[3]),  pk2f(p1[4],p1[5]),  pk2f(p1[6],p1[7]) };
    v4i i11 = { pk2f(p1[8],p1[9]),  pk2f(p1[10],p1[11]),pk2f(p1[12],p1[13]),pk2f(p1[14],p1[15]) };
    v8s pb00 = __builtin_bit_cast(v8s, i00);
    v8s pb01 = __builtin_bit_cast(v8s, i01);
    v8s pb10 = __builtin_bit_cast(v8s, i10);
    v8s pb11 = __builtin_bit_cast(v8s, i11);

    // O^T += V^T . P^T   (A k-slots read permuted-key chunks: q = st*4 + kc*2 + h2)
#pragma unroll
    for (int st = 0; st < 2; st++) {
#pragma unroll
      for (int kc = 0; kc < 2; kc++) {
        const int q = st * 4 + kc * 2 + h2;
        v8s avA = *(const v8s*)(vc_ + ln * 64 + ((q ^ (ln & 7)) * 8));
        v8s avB = *(const v8s*)(vc_ + (32 + ln) * 64 + ((q ^ (ln & 7)) * 8));
        v8s pb = st ? (kc ? pb11 : pb10) : (kc ? pb01 : pb00);
        accA = mfma32(avA, pb, accA);
        accB = mfma32(avB, pb, accB);
      }
    }
  }

  // epilogue: normalize, swizzled LDS transpose, coalesced bf16 store
  const float lfull = lpart + __shfl_xor(lpart, 32);
  const float linv = 1.0f / lfull;
  bf16* epw = ep[w];
  const int swz = (ln >> 3) & 3;
#pragma unroll
  for (int r = 0; r < 16; r += 2) {
    const int off = (r & 3) + 4 * h2;          // even -> 4B-aligned pair
    const int spA = (r >> 2) ^ swz;
    const int vA = pk2f(accA[r] * linv, accA[r + 1] * linv);
    const int vB = pk2f(accB[r] * linv, accB[r + 1] * linv);
    *(int*)(epw + ln * 72 + spA * 8 + off) = vA;
    *(int*)(epw + ln * 72 + (4 + spA) * 8 + off) = vB;
  }
  __syncthreads();
#pragma unroll
  for (int i = 0; i < 4; i++) {
    const int flat = i * 64 + l;
    const int qr = flat >> 3, sd = flat & 7;
    const int pos = 4 * (sd >> 2) + ((sd & 3) ^ ((qr >> 3) & 3));
    v8s val = *(const v8s*)(epw + qr * 72 + pos * 8);
    *(v8s*)(Ow + ((size_t)b * S_ + qbase + qr) * D_ + h * DK_ + sd * 8) = val;
  }
}

// ---------- projection: Out[m][n] = sum_k o[m][k]*Wo[n][k], f32 out ----------
// 64x64 tile, BK=64, mfma32, dbuf, grid (64,16)=1024 blocks -> 16 waves/CU
__global__ __launch_bounds__(256, 4) void proj3_kernel(
    const bf16* __restrict__ A, const bf16* __restrict__ Wo, float* __restrict__ Out)
{
  __shared__ __align__(16) bf16 aa[2][64 * 64];
  __shared__ __align__(16) bf16 bb[2][64 * 64];

  const int t = threadIdx.x;
  const int w = t >> 6, l = t & 63, h2 = l >> 5, ln = l & 31;
  const int m0 = blockIdx.x * 64, n0 = blockIdx.y * 64;
  const int wm = (w & 1) * 32, wn = (w >> 1) * 32;

  v16f acc;
#pragma unroll
  for (int r = 0; r < 16; r++) acc[r] = 0.f;

  // prologue
#pragma unroll
  for (int j = 0; j < 2; j++) {
    const int flat = j * 256 + t, row = flat >> 3, sp = flat & 7;
    gl2lds16(A  + (size_t)(m0 + row) * D_ + ((sp ^ (row & 7)) * 8), &aa[0][flat * 8]);
    gl2lds16(Wo + (size_t)(n0 + row) * D_ + ((sp ^ (row & 7)) * 8), &bb[0][flat * 8]);
  }

  int it = 0;
  for (int k0 = 0; k0 < D_; k0 += 64, it ^= 1) {
    __syncthreads();
    if (k0 + 64 < D_) {
#pragma unroll
      for (int j = 0; j < 2; j++) {
        const int flat = j * 256 + t, row = flat >> 3, sp = flat & 7;
        gl2lds16(A  + (size_t)(m0 + row) * D_ + (k0 + 64) + ((sp ^ (row & 7)) * 8),
                 &aa[it ^ 1][flat * 8]);
        gl2lds16(Wo + (size_t)(n0 + row) * D_ + (k0 + 64) + ((sp ^ (row & 7)) * 8),
                 &bb[it ^ 1][flat * 8]);
      }
    }
    const bf16* ac = aa[it];
    const bf16* bc = bb[it];
#pragma unroll
    for (int c = 0; c < 4; c++) {
      const int sd = 2 * c + h2;
      v8s av = *(const v8s*)(ac + (wm + ln) * 64 + ((sd ^ (ln & 7)) * 8));
      v8s bv = *(const v8s*)(bc + (wn + ln) * 64 + ((sd ^ (ln & 7)) * 8));
      acc = mfma32(av, bv, acc);
    }
  }

  // C layout: col n = ln, row m = (r&3) + 4*h2 + 8*(r>>2)
#pragma unroll
  for (int r = 0; r < 16; r++) {
    const int row = m0 + wm + (r & 3) + 4 * h2 + 8 * (r >> 2);
    Out[(size_t)row * D_ + n0 + wn + ln] = acc[r];
  }
}

extern "C" void kernel_launch(void* const* d_in, const int* in_sizes, int n_in,
                              void* d_out, int out_size, void* d_ws, size_t ws_size,
                              hipStream_t stream) {
  (void)in_sizes; (void)n_in; (void)out_size; (void)ws_size;
  const float* Q  = (const float*)d_in[0];
  const float* K  = (const float*)d_in[1];
  const float* V  = (const float*)d_in[2];
  const float* Wo = (const float*)d_in[3];
  float* out = (float*)d_out;

  bf16* kb   = (bf16*)d_ws;                        // 8 MB: K bf16 [bh][s][64]
  bf16* vt   = kb + (size_t)4 * 1024 * 1024;       // 8 MB: V^T bf16 [bh][64][s] (key-permuted)
  bf16* ows  = vt + (size_t)4 * 1024 * 1024;       // 8 MB: o bf16 [4096][1024]
  bf16* wo_b = ows + (size_t)4 * 1024 * 1024;      // 2 MB: Wo bf16

  cvt_k_kernel <<<dim3(2048),   256, 0, stream>>>(K, kb);
  tv_kernel    <<<dim3(32, 32), 256, 0, stream>>>(V, vt);
  cvt_wo_kernel<<<dim3(1024),   256, 0, stream>>>(Wo, wo_b);
  attn3_kernel <<<dim3(32, 16), 256, 0, stream>>>(Q, kb, vt, ows);
  proj3_kernel <<<dim3(64, 16), 256, 0, stream>>>(ows, wo_b, out);
}

// Round 7
// 176.807 us; speedup vs baseline: 1.1318x; 1.0074x over previous
//
#include <hip/hip_runtime.h>
#include <hip/hip_bf16.h>

#define B_ 2
#define S_ 2048
#define D_ 1024
#define H_ 16
#define DK_ 64

typedef __hip_bfloat16 bf16;
typedef short v8s __attribute__((ext_vector_type(8)));
typedef short v4s __attribute__((ext_vector_type(4)));
typedef float v4f __attribute__((ext_vector_type(4)));
typedef float v16f __attribute__((ext_vector_type(16)));
typedef int   v4i __attribute__((ext_vector_type(4)));
typedef int   v2i __attribute__((ext_vector_type(2)));

static __device__ __forceinline__ v16f mfma32(v8s a, v8s b, v16f c) {
  return __builtin_amdgcn_mfma_f32_32x32x16_bf16(a, b, c, 0, 0, 0);
}
static __device__ __forceinline__ void gl2lds16(const void* g, void* l) {
  __builtin_amdgcn_global_load_lds((const __attribute__((address_space(1))) void*)g,
                                   (__attribute__((address_space(3))) void*)l,
                                   16, 0, 0);
}
static __device__ __forceinline__ short f2bf(float x) {  // RNE (pre-passes)
  return (short)__builtin_bit_cast(unsigned short, __float2bfloat16(x));
}
// fast bf16 pair pack: round-half-up then v_perm_b32
static __device__ __forceinline__ int pk2f(float lo, float hi) {
  unsigned a = __builtin_bit_cast(unsigned, lo) + 0x8000u;
  unsigned b = __builtin_bit_cast(unsigned, hi) + 0x8000u;
  return (int)__builtin_amdgcn_perm(b, a, 0x07060302u);
}
static __device__ __forceinline__ float bf2f(short s) {
  return __builtin_bit_cast(float, ((unsigned)(unsigned short)s) << 16);
}

// ---------- merged pre-pass: K->bf16 [bh][s][64] | V->V^T bf16 permuted | Wo->bf16 ----------
// blocks [0,2048): K cvt; [2048,3072): V transpose; [3072,4096): Wo cvt
__global__ __launch_bounds__(256) void pre_kernel(
    const float* __restrict__ K, const float* __restrict__ V,
    const float* __restrict__ Wo, bf16* __restrict__ Kb,
    bf16* __restrict__ Vt, bf16* __restrict__ Wb)
{
  __shared__ __align__(16) bf16 td[64 * 72];
  const int t = threadIdx.x;
  const int bx = blockIdx.x;

  if (bx < 2048) {           // ---- K: [b][s][h*64+d] -> [bh][s][64]
    const int idx = bx * 256 + t;
    const int seg = idx & 7;
    const int rest = idx >> 3;
    const int h = rest & 15;
    const int bs = rest >> 4;
    const float* src = K + (size_t)bs * D_ + h * 64 + seg * 8;
    v4f x = *(const v4f*)src, y = *(const v4f*)(src + 4);
    v8s r;
    r[0]=f2bf(x[0]); r[1]=f2bf(x[1]); r[2]=f2bf(x[2]); r[3]=f2bf(x[3]);
    r[4]=f2bf(y[0]); r[5]=f2bf(y[1]); r[6]=f2bf(y[2]); r[7]=f2bf(y[3]);
    const int b = bs >> 11, s = bs & 2047;
    *(v8s*)(Kb + ((size_t)(b * H_ + h) * S_ + s) * DK_ + seg * 8) = r;
  } else if (bx < 3072) {    // ---- V -> V^T [bh][64][2048], key-permuted within 32-groups
    const int idx = bx - 2048;
    const int bh = idx >> 5, b = bh >> 4, h = bh & 15;
    const int s0 = (idx & 31) * 64;
    const int srow = t >> 2;
    const int cs = t & 3;
    const float* vp = V + (size_t)(b * S_ + s0 + srow) * D_ + h * 64 + cs * 16;
#pragma unroll
    for (int j = 0; j < 4; j++) {
      v4f x = *(const v4f*)(vp + j * 4);
#pragma unroll
      for (int jj = 0; jj < 4; jj++)
        td[(cs * 16 + j * 4 + jj) * 72 + srow] = __float2bfloat16(x[jj]);
    }
    __syncthreads();
    const int d = t >> 2;
#pragma unroll
    for (int a2 = 0; a2 < 4; a2++) {
      const int pos = cs * 16 + a2 * 4;
      const int g = pos >> 5;
      const int a = (pos >> 2) & 7;
      const int kbase = g * 32 + ((a >> 2) << 4) + ((a & 1) << 3) + (((a >> 1) & 1) << 2);
      v4s val = *(const v4s*)(td + d * 72 + kbase);
      *(v4s*)(Vt + ((size_t)bh * DK_ + d) * S_ + s0 + pos) = val;
    }
  } else {                   // ---- Wo cvt
    const int i = ((bx - 3072) * 256 + t) * 4;
    v4f a = *(const v4f*)(Wo + i);
    v4s r;
    r[0]=f2bf(a[0]); r[1]=f2bf(a[1]); r[2]=f2bf(a[2]); r[3]=f2bf(a[3]);
    *(v4s*)((short*)Wb + i) = r;
  }
}

// ---------- flash attention, key-split: grid (32 bh, 16 qtile, 2 keyhalf) ----------
// each block: 4 waves x 32 q x 1024 keys; writes partial-normalized O + partial l
__global__ __launch_bounds__(256, 4) void attn4_kernel(
    const float* __restrict__ Q, const bf16* __restrict__ Kb,
    const bf16* __restrict__ Vt, bf16* __restrict__ Op0,
    bf16* __restrict__ Op1, float* __restrict__ Lp)
{
  __shared__ __align__(16) bf16 kk[2][64 * 64];   // 16 KB (aliased by epilogue)
  __shared__ __align__(16) bf16 vv[2][64 * 64];   // 16 KB

  const int t = threadIdx.x;
  const int w = t >> 6, l = t & 63, h2 = l >> 5, ln = l & 31;
  const int bh = blockIdx.x, b = bh >> 4, h = bh & 15;
  const int qbase = blockIdx.y * 128 + w * 32;
  const int z = blockIdx.z;
  const int kb0 = z << 10;

  const bf16* Kbh = Kb + (size_t)bh * (S_ * DK_);
  const bf16* Vbh = Vt + (size_t)bh * (DK_ * S_);

  // Q^T B-frags, scale folded
  const float sc = 0.18033688011112042f;  // (1/sqrt(64)) * log2(e)
  v8s bq[4];
  {
    const float* qp = Q + ((size_t)b * S_ + qbase + ln) * D_ + h * DK_ + h2 * 8;
#pragma unroll
    for (int c = 0; c < 4; c++) {
      v4f x = *(const v4f*)(qp + c * 16);
      v4f y = *(const v4f*)(qp + c * 16 + 4);
      v4i r = { pk2f(x[0]*sc, x[1]*sc), pk2f(x[2]*sc, x[3]*sc),
                pk2f(y[0]*sc, y[1]*sc), pk2f(y[2]*sc, y[3]*sc) };
      bq[c] = __builtin_bit_cast(v8s, r);
    }
  }

  v16f accA, accB;
#pragma unroll
  for (int r = 0; r < 16; r++) { accA[r] = 0.f; accB[r] = 0.f; }
  float lpart = 0.f;

  // prologue: stage first tile into buf 0
#pragma unroll
  for (int j = 0; j < 2; j++) {
    const int flat = j * 256 + t, row = flat >> 3, sp = flat & 7;
    gl2lds16(Kbh + (size_t)(kb0 + row) * DK_ + ((sp ^ (row & 7)) * 8), &kk[0][flat * 8]);
    gl2lds16(Vbh + (size_t)row * S_ + kb0 + ((sp ^ (row & 7)) * 8), &vv[0][flat * 8]);
  }

  int it = 0;
  for (int kb = kb0; kb < kb0 + 1024; kb += 64, it ^= 1) {
    __syncthreads();
    if (kb + 64 < kb0 + 1024) {
#pragma unroll
      for (int j = 0; j < 2; j++) {
        const int flat = j * 256 + t, row = flat >> 3, sp = flat & 7;
        gl2lds16(Kbh + (size_t)(kb + 64 + row) * DK_ + ((sp ^ (row & 7)) * 8),
                 &kk[it ^ 1][flat * 8]);
        gl2lds16(Vbh + (size_t)row * S_ + (kb + 64) + ((sp ^ (row & 7)) * 8),
                 &vv[it ^ 1][flat * 8]);
      }
    }
    const bf16* kc_ = kk[it];
    const bf16* vc_ = vv[it];

    v16f s0, s1;
#pragma unroll
    for (int r = 0; r < 16; r++) { s0[r] = 0.f; s1[r] = 0.f; }
#pragma unroll
    for (int c = 0; c < 4; c++) {
      const int sd = 2 * c + h2;
      v8s a0 = *(const v8s*)(kc_ + ln * 64 + ((sd ^ (ln & 7)) * 8));
      v8s a1 = *(const v8s*)(kc_ + (32 + ln) * 64 + ((sd ^ (ln & 7)) * 8));
      s0 = mfma32(a0, bq[c], s0);
      s1 = mfma32(a1, bq[c], s1);
    }

    float p0[16], p1[16];
#pragma unroll
    for (int r = 0; r < 16; r++) { p0[r] = exp2f(s0[r]); p1[r] = exp2f(s1[r]); }
    float su = 0.f;
#pragma unroll
    for (int r = 0; r < 16; r++) su += p0[r] + p1[r];
    lpart += su;

    v4i i00 = { pk2f(p0[0],p0[1]),  pk2f(p0[2],p0[3]),  pk2f(p0[4],p0[5]),  pk2f(p0[6],p0[7]) };
    v4i i01 = { pk2f(p0[8],p0[9]),  pk2f(p0[10],p0[11]),pk2f(p0[12],p0[13]),pk2f(p0[14],p0[15]) };
    v4i i10 = { pk2f(p1[0],p1[1]),  pk2f(p1[2],p1[3]),  pk2f(p1[4],p1[5]),  pk2f(p1[6],p1[7]) };
    v4i i11 = { pk2f(p1[8],p1[9]),  pk2f(p1[10],p1[11]),pk2f(p1[12],p1[13]),pk2f(p1[14],p1[15]) };
    v8s pb00 = __builtin_bit_cast(v8s, i00);
    v8s pb01 = __builtin_bit_cast(v8s, i01);
    v8s pb10 = __builtin_bit_cast(v8s, i10);
    v8s pb11 = __builtin_bit_cast(v8s, i11);

#pragma unroll
    for (int st = 0; st < 2; st++) {
#pragma unroll
      for (int kc = 0; kc < 2; kc++) {
        const int q = st * 4 + kc * 2 + h2;
        v8s avA = *(const v8s*)(vc_ + ln * 64 + ((q ^ (ln & 7)) * 8));
        v8s avB = *(const v8s*)(vc_ + (32 + ln) * 64 + ((q ^ (ln & 7)) * 8));
        v8s pb = st ? (kc ? pb11 : pb10) : (kc ? pb01 : pb00);
        accA = mfma32(avA, pb, accA);
        accB = mfma32(avB, pb, accB);
      }
    }
  }

  // epilogue: normalize by PARTIAL l, transpose via LDS (aliases kk), store + l
  __syncthreads();   // all waves done reading kk before aliasing
  const float lfull = lpart + __shfl_xor(lpart, 32);
  const float linv = 1.0f / lfull;
  bf16* epw = &kk[0][0] + w * 2048;  // 32 q x 64 d, XOR-swizzled segs
#pragma unroll
  for (int r = 0; r < 16; r += 4) {
    const int off = 4 * h2;                     // element offset within seg (0 or 4)
    const int sgA = (r >> 2) ^ (ln & 3);        // phys seg 0..3
    const int sgB = 4 + sgA;                    // phys seg 4..7
    v2i pa = { pk2f(accA[r]*linv,   accA[r+1]*linv),
               pk2f(accA[r+2]*linv, accA[r+3]*linv) };
    v2i pb = { pk2f(accB[r]*linv,   accB[r+1]*linv),
               pk2f(accB[r+2]*linv, accB[r+3]*linv) };
    *(v2i*)(epw + ln * 64 + sgA * 8 + off) = pa;
    *(v2i*)(epw + ln * 64 + sgB * 8 + off) = pb;
  }
  if (h2 == 0)
    Lp[((size_t)z * 32 + bh) * S_ + qbase + ln] = lfull;

  bf16* Op = z ? Op1 : Op0;
#pragma unroll
  for (int i = 0; i < 4; i++) {
    const int flat = i * 64 + l;
    const int qr = flat >> 3, sd = flat & 7;
    const int phys = ((sd & 3) ^ (qr & 3)) | (sd & 4);
    v8s val = *(const v8s*)(epw - w * 2048 + (w * 32 + qr) * 64 + phys * 8);
    *(v8s*)(Op + ((size_t)b * S_ + qbase - w * 32 + w * 32 + qr) * D_ + h * DK_ + sd * 8) = val;
  }
}

// ---------- merge: o = (l0*o0 + l1*o1)/(l0+l1), bf16 out ----------
__global__ __launch_bounds__(256) void merge_kernel(
    const bf16* __restrict__ Op0, const bf16* __restrict__ Op1,
    const float* __restrict__ Lp, bf16* __restrict__ O)
{
  const int flat = blockIdx.x * 256 + threadIdx.x;
  const int qrow = flat >> 7;          // 0..4095
  const int seg = flat & 127;          // 8 elems
  const int b = qrow >> 11, s = qrow & 2047;
  const int h = seg >> 3;
  const int bh = b * H_ + h;
  const float l0 = Lp[(size_t)bh * S_ + s];
  const float l1 = Lp[(size_t)(32 + bh) * S_ + s];
  const float inv = 1.0f / (l0 + l1);
  const float w0 = l0 * inv, w1 = l1 * inv;
  const size_t off = (size_t)qrow * D_ + seg * 8;
  v8s a = *(const v8s*)(Op0 + off);
  v8s c = *(const v8s*)(Op1 + off);
  v4i r;
#pragma unroll
  for (int j = 0; j < 4; j++) {
    float lo = w0 * bf2f(a[2*j])   + w1 * bf2f(c[2*j]);
    float hi = w0 * bf2f(a[2*j+1]) + w1 * bf2f(c[2*j+1]);
    r[j] = pk2f(lo, hi);
  }
  *(v8s*)(O + off) = __builtin_bit_cast(v8s, r);
}

// ---------- projection: Out[m][n] = sum_k o[m][k]*Wo[n][k], f32 out ----------
__global__ __launch_bounds__(256, 4) void proj3_kernel(
    const bf16* __restrict__ A, const bf16* __restrict__ Wo, float* __restrict__ Out)
{
  __shared__ __align__(16) bf16 aa[2][64 * 64];
  __shared__ __align__(16) bf16 bb[2][64 * 64];

  const int t = threadIdx.x;
  const int w = t >> 6, l = t & 63, h2 = l >> 5, ln = l & 31;
  const int m0 = blockIdx.x * 64, n0 = blockIdx.y * 64;
  const int wm = (w & 1) * 32, wn = (w >> 1) * 32;

  v16f acc;
#pragma unroll
  for (int r = 0; r < 16; r++) acc[r] = 0.f;

#pragma unroll
  for (int j = 0; j < 2; j++) {
    const int flat = j * 256 + t, row = flat >> 3, sp = flat & 7;
    gl2lds16(A  + (size_t)(m0 + row) * D_ + ((sp ^ (row & 7)) * 8), &aa[0][flat * 8]);
    gl2lds16(Wo + (size_t)(n0 + row) * D_ + ((sp ^ (row & 7)) * 8), &bb[0][flat * 8]);
  }

  int it = 0;
  for (int k0 = 0; k0 < D_; k0 += 64, it ^= 1) {
    __syncthreads();
    if (k0 + 64 < D_) {
#pragma unroll
      for (int j = 0; j < 2; j++) {
        const int flat = j * 256 + t, row = flat >> 3, sp = flat & 7;
        gl2lds16(A  + (size_t)(m0 + row) * D_ + (k0 + 64) + ((sp ^ (row & 7)) * 8),
                 &aa[it ^ 1][flat * 8]);
        gl2lds16(Wo + (size_t)(n0 + row) * D_ + (k0 + 64) + ((sp ^ (row & 7)) * 8),
                 &bb[it ^ 1][flat * 8]);
      }
    }
    const bf16* ac = aa[it];
    const bf16* bc = bb[it];
#pragma unroll
    for (int c = 0; c < 4; c++) {
      const int sd = 2 * c + h2;
      v8s av = *(const v8s*)(ac + (wm + ln) * 64 + ((sd ^ (ln & 7)) * 8));
      v8s bv = *(const v8s*)(bc + (wn + ln) * 64 + ((sd ^ (ln & 7)) * 8));
      acc = mfma32(av, bv, acc);
    }
  }

#pragma unroll
  for (int r = 0; r < 16; r++) {
    const int row = m0 + wm + (r & 3) + 4 * h2 + 8 * (r >> 2);
    Out[(size_t)row * D_ + n0 + wn + ln] = acc[r];
  }
}

extern "C" void kernel_launch(void* const* d_in, const int* in_sizes, int n_in,
                              void* d_out, int out_size, void* d_ws, size_t ws_size,
                              hipStream_t stream) {
  (void)in_sizes; (void)n_in; (void)out_size; (void)ws_size;
  const float* Q  = (const float*)d_in[0];
  const float* K  = (const float*)d_in[1];
  const float* V  = (const float*)d_in[2];
  const float* Wo = (const float*)d_in[3];
  float* out = (float*)d_out;

  bf16* base = (bf16*)d_ws;
  bf16* kb   = base;                     // 8 MB  (reused as merged-o after attn)
  bf16* vt   = base + (size_t)4  * 1024 * 1024;  // 8 MB
  bf16* wo_b = base + (size_t)8  * 1024 * 1024;  // 2 MB
  bf16* op0  = base + (size_t)9  * 1024 * 1024;  // 8 MB  partial O (keys 0..1023)
  bf16* op1  = base + (size_t)13 * 1024 * 1024;  // 8 MB  partial O (keys 1024..2047)
  float* lp  = (float*)(base + (size_t)17 * 1024 * 1024); // 512 KB partial l
  bf16* ows  = kb;                       // merged o aliases kb (kb dead after attn)

  pre_kernel  <<<dim3(4096),       256, 0, stream>>>(K, V, Wo, kb, vt, wo_b);
  attn4_kernel<<<dim3(32, 16, 2),  256, 0, stream>>>(Q, kb, vt, op0, op1, lp);
  merge_kernel<<<dim3(2048),       256, 0, stream>>>(op0, op1, lp, ows);
  proj3_kernel<<<dim3(64, 16),     256, 0, stream>>>(ows, wo_b, out);
}